// Round 1
// 3228.235 us; speedup vs baseline: 1.5507x; 1.5507x over previous
//
#include <hip/hip_runtime.h>
#include <stdint.h>
#include <math.h>

// ---------------------------------------------------------------------------
// p_net forward on MI355X.  B=4096 boards, N=81 cells, D=128, H=4 heads.
// Round 7: conv3 moved to MFMA (mfma_f32_16x16x32_f16) with split-fp16
// precision (hi + lo*2^-11, scaled-lo accumulator -> ~fp32 accuracy).
// conv2 table output staged once in LDS as fp16 hi/lo, XOR-swizzled
// (byte ^= (row&7)<<4) for conflict-free ds_read_b128 B-fragments.
// Weights pre-packed in fragment order by k_prep (reuses old w3r slot).
// Outputs (concat, float32): pos[4096], num[4096], asc[4096*81*81].
// ---------------------------------------------------------------------------

#define NB 4096

typedef unsigned short u16;
typedef _Float16 f16x8 __attribute__((ext_vector_type(8)));
typedef float f32x4 __attribute__((ext_vector_type(4)));

__device__ __forceinline__ float silu_f(float v) {
  return v / (1.0f + expf(-v));
}

__device__ __forceinline__ float4 zero4() { return make_float4(0.f,0.f,0.f,0.f); }

__device__ __forceinline__ void fma4b(float4& a, const float s, const float4 x) {
  a.x = fmaf(s, x.x, a.x); a.y = fmaf(s, x.y, a.y);
  a.z = fmaf(s, x.z, a.z); a.w = fmaf(s, x.w, a.w);
}

// sequential dot-accumulate: a += w·x, 4 fmaf, scalar accumulator
__device__ __forceinline__ void dacc(float& a, const float4 w, const float4 x) {
  a = fmaf(w.x, x.x, a); a = fmaf(w.y, x.y, a);
  a = fmaf(w.z, x.z, a); a = fmaf(w.w, x.w, a);
}

// ---------------- Threefry-2x32 (JAX partitionable) ------------------------
__device__ __forceinline__ void tf_round(uint32_t& x0, uint32_t& x1, int r) {
  x0 += x1;
  x1 = (x1 << r) | (x1 >> (32 - r));
  x1 ^= x0;
}

__device__ __forceinline__ void threefry2x32(uint32_t k0, uint32_t k1,
                                             uint32_t x0, uint32_t x1,
                                             uint32_t& o0, uint32_t& o1) {
  uint32_t k2 = k0 ^ k1 ^ 0x1BD11BDAu;
  x0 += k0; x1 += k1;
  tf_round(x0,x1,13); tf_round(x0,x1,15); tf_round(x0,x1,26); tf_round(x0,x1,6);
  x0 += k1; x1 += k2 + 1u;
  tf_round(x0,x1,17); tf_round(x0,x1,29); tf_round(x0,x1,16); tf_round(x0,x1,24);
  x0 += k2; x1 += k0 + 2u;
  tf_round(x0,x1,13); tf_round(x0,x1,15); tf_round(x0,x1,26); tf_round(x0,x1,6);
  x0 += k0; x1 += k1 + 3u;
  tf_round(x0,x1,17); tf_round(x0,x1,29); tf_round(x0,x1,16); tf_round(x0,x1,24);
  x0 += k1; x1 += k2 + 4u;
  tf_round(x0,x1,13); tf_round(x0,x1,15); tf_round(x0,x1,26); tf_round(x0,x1,6);
  x0 += k2; x1 += k0 + 5u;
  o0 = x0; o1 = x1;
}

__device__ __forceinline__ void jax_split42(uint32_t& k1a, uint32_t& k1b,
                                            uint32_t& k2a, uint32_t& k2b) {
  threefry2x32(0u, 42u, 0u, 0u, k1a, k1b);
  threefry2x32(0u, 42u, 0u, 1u, k2a, k2b);
}

__device__ __forceinline__ uint32_t jax_randbits(uint32_t ka, uint32_t kb,
                                                 uint32_t i) {
  uint32_t o0, o1;
  threefry2x32(ka, kb, 0u, i, o0, o1);
  return o0 ^ o1;
}

__device__ __forceinline__ float jax_gumbel_bits(uint32_t bits) {
  float f = __uint_as_float((bits >> 9) | 0x3f800000u) - 1.0f;
  const float tiny = 1.17549435e-38f;
  float u = fmaxf(tiny, f + tiny);
  return -logf(-logf(u));
}

// ---------------- prep: conv tables + fragment-packed conv3 weights --------
// WAh/WAl layout: [(d*4 + kc)*8 + ot][lane 0..63][j 0..7] fp16 bits.
// Fragment semantics: A[m][k], m = lane&15 (oc within 16-tile),
// k-slot = (lane>>4)*8 + j  -> ic = kc*32 + (lane>>4)*8 + j.
__global__ __launch_bounds__(256) void k_prep(
    const float* __restrict__ c1_w, const float* __restrict__ c1_b,
    const float* __restrict__ c2_w, const float* __restrict__ c3_w,
    const float* __restrict__ out_w, const float* __restrict__ l1_w,
    const float* __restrict__ l2_w,
    float* __restrict__ T2e, u16* __restrict__ WAh, u16* __restrict__ WAl,
    float* __restrict__ owT, float* __restrict__ l1T, float* __restrict__ l2T)
{
  int idx = blockIdx.x * 256 + threadIdx.x;
  if (idx < 9*11*128) {
    int oc = idx & 127;
    int t  = idx >> 7;
    int g  = t % 11;
    int d  = t / 11;
    float acc = 0.f;
    if (g < 10) {
      int di = d / 3, dj = d % 3;
      for (int ic = 0; ic < 64; ++ic) {
        float x1 = c1_w[ic*10 + g] + c1_b[ic];
        acc += c2_w[((oc*64 + ic)*3 + di)*3 + dj] * x1;
      }
    }
    T2e[idx] = acc;
  } else if (idx < 160128) {
    int j  = idx - 12672;          // 0..147455
    int jj = j & 7;
    int t  = j >> 3;               // ((d*4+kc)*8+ot)*64 + lane
    int ln = t & 63;
    int t2 = t >> 6;               // (d*4+kc)*8 + ot
    int ot = t2 & 7;
    int t3 = t2 >> 3;              // d*4 + kc
    int kc = t3 & 3;
    int d  = t3 >> 2;
    int oc = ot*16 + (ln & 15);
    int ic = kc*32 + (ln >> 4)*8 + jj;
    float w = c3_w[(oc*128 + ic)*9 + d];
    _Float16 wh = (_Float16)w;
    _Float16 wl = (_Float16)((w - (float)wh) * 2048.0f);
    union { _Float16 f; u16 u; } ch, cl;
    ch.f = wh; cl.f = wl;
    WAh[j] = ch.u; WAl[j] = cl.u;
  } else if (idx < 176512) {
    int j = idx - 160128;                      // j = k*128 + oc
    owT[j] = out_w[(j & 127)*128 + (j >> 7)];
  } else if (idx < 192896) {
    int j = idx - 176512;
    l1T[j] = l1_w[(j & 127)*128 + (j >> 7)];
  } else if (idx < 209280) {
    int j = idx - 192896;
    l2T[j] = l2_w[(j & 127)*128 + (j >> 7)];
  }
}

// ---------------- stem: digits -> conv2(table, fp16 hi/lo in LDS)
//                  -> conv3 on MFMA (split-fp16) -> +emb -------------------
// 256 threads (4 waves) / board. LDS: x2h/x2l [121 rows][128 ch] fp16,
// XOR-swizzled within row: byte ^= ((row&7)<<4). Pad rows are zero.
__global__ __launch_bounds__(256, 2) void k_stem(
    const float* __restrict__ s, const float* __restrict__ T2e,
    const float* __restrict__ c2_b,
    const u16* __restrict__ WAh, const u16* __restrict__ WAl,
    const float* __restrict__ c3_b, const float* __restrict__ emb,
    float* __restrict__ xout, int* __restrict__ digits)
{
  __shared__ __align__(16) u16 x2h[121*128];   // 30976 B
  __shared__ __align__(16) u16 x2l[121*128];   // 30976 B
  __shared__ int dg[121];                      // padded digit grid, 10 = pad
  const int b   = blockIdx.x;
  const int tid = threadIdx.x;

  // zero-fill activation buffers (pad rows must stay zero) + dg sentinel
  for (int i = tid; i < 1936; i += 256) {
    ((uint4*)x2h)[i] = make_uint4(0u,0u,0u,0u);
    ((uint4*)x2l)[i] = make_uint4(0u,0u,0u,0u);
  }
  if (tid < 121) dg[tid] = 10;
  __syncthreads();

  if (tid < 81) {
    const float* sp = s + (size_t)b*810 + tid;
    float dv = 0.f;
    #pragma unroll
    for (int c = 1; c < 10; ++c) dv += (float)c * sp[c*81];
    int d = (int)(dv + 0.5f);
    dg[(tid/9 + 1)*11 + (tid%9 + 1)] = d;
    digits[b*81 + tid] = d;
  }
  __syncthreads();

  // ---- conv2 via table: 81 cells x 16 chunks of 8 channels ----
  for (int i = tid; i < 1296; i += 256) {
    const int p  = i >> 4;          // 0..80
    const int k8 = i & 15;          // channel chunk
    const int r0 = p / 9, c0 = p - r0*9;
    const float4 b0 = *(const float4*)(c2_b + k8*8);
    const float4 b1 = *(const float4*)(c2_b + k8*8 + 4);
    float a0=b0.x, a1=b0.y, a2=b0.z, a3=b0.w;
    float a4=b1.x, a5=b1.y, a6=b1.z, a7=b1.w;
    #pragma unroll
    for (int d = 0; d < 9; ++d) {
      const int g = dg[(r0 + d/3)*11 + (c0 + d%3)];
      const float* tp = T2e + (size_t)(d*11 + g)*128 + k8*8;
      const float4 t0 = *(const float4*)tp;
      const float4 t1 = *(const float4*)(tp + 4);
      a0 += t0.x; a1 += t0.y; a2 += t0.z; a3 += t0.w;
      a4 += t1.x; a5 += t1.y; a6 += t1.z; a7 += t1.w;
    }
    float v[8];
    v[0]=silu_f(a0); v[1]=silu_f(a1); v[2]=silu_f(a2); v[3]=silu_f(a3);
    v[4]=silu_f(a4); v[5]=silu_f(a5); v[6]=silu_f(a6); v[7]=silu_f(a7);
    f16x8 hv, lv;
    #pragma unroll
    for (int j = 0; j < 8; ++j) {
      _Float16 h = (_Float16)v[j];
      hv[j] = h;
      lv[j] = (_Float16)((v[j] - (float)h) * 2048.0f);
    }
    const int row = (r0 + 1)*11 + (c0 + 1);
    const uint32_t bo = (uint32_t)row*256u + (uint32_t)((k8*16) ^ ((row & 7) << 4));
    *(f16x8*)((char*)x2h + bo) = hv;
    *(f16x8*)((char*)x2l + bo) = lv;
  }
  __syncthreads();

  // ---- conv3 on MFMA: D[128 oc][96 cells] = sum_d W_d · x2(shifted) ----
  // 48 tiles (8 octiles x 6 ntiles); wave owns 4 octiles x 3 ntiles.
  const int ln  = tid & 63;
  const int wv  = tid >> 6;
  const int lg  = ln >> 4;          // lane group 0..3
  const int lr  = ln & 15;
  const int otB = (wv & 1) * 4;     // octile base
  const int ntB = (wv >> 1) * 3;    // ntile base

  f32x4 accH[4][3];
  f32x4 accC[4][3];
  #pragma unroll
  for (int ot = 0; ot < 4; ++ot)
    #pragma unroll
    for (int nt = 0; nt < 3; ++nt) {
      accH[ot][nt] = (f32x4){0.f,0.f,0.f,0.f};
      accC[ot][nt] = (f32x4){0.f,0.f,0.f,0.f};
    }

  int pbase[3];
  #pragma unroll
  for (int nt = 0; nt < 3; ++nt) {
    const int c = (ntB + nt)*16 + lr;
    pbase[nt] = (c < 81) ? (c/9)*11 + (c%9) : 0;   // invalid lanes -> cell 0 (unstored)
  }
  const char* x2hB = (const char*)x2h;
  const char* x2lB = (const char*)x2l;

  for (int d = 0; d < 9; ++d) {
    const int off = (d/3)*11 + (d - (d/3)*3);
    int rowv[3];
    #pragma unroll
    for (int nt = 0; nt < 3; ++nt) rowv[nt] = pbase[nt] + off;
    #pragma unroll
    for (int kc = 0; kc < 4; ++kc) {
      const int kb = kc*64 + lg*16;
      f16x8 Bh[3], Bl[3];
      #pragma unroll
      for (int nt = 0; nt < 3; ++nt) {
        const uint32_t o = (uint32_t)rowv[nt]*256u +
                           (uint32_t)(kb ^ ((rowv[nt] & 7) << 4));
        Bh[nt] = *(const f16x8*)(x2hB + o);
        Bl[nt] = *(const f16x8*)(x2lB + o);
      }
      const int abase = (((d*4 + kc)*8 + otB)*64 + ln)*8;
      f16x8 Ah[4], Al[4];
      #pragma unroll
      for (int ot = 0; ot < 4; ++ot) {
        Ah[ot] = *(const f16x8*)(WAh + abase + ot*512);
        Al[ot] = *(const f16x8*)(WAl + abase + ot*512);
      }
      #pragma unroll
      for (int ot = 0; ot < 4; ++ot)
        #pragma unroll
        for (int nt = 0; nt < 3; ++nt) {
          accH[ot][nt] = __builtin_amdgcn_mfma_f32_16x16x32_f16(
              Ah[ot], Bh[nt], accH[ot][nt], 0, 0, 0);
          accC[ot][nt] = __builtin_amdgcn_mfma_f32_16x16x32_f16(
              Ah[ot], Bl[nt], accC[ot][nt], 0, 0, 0);
          accC[ot][nt] = __builtin_amdgcn_mfma_f32_16x16x32_f16(
              Al[ot], Bh[nt], accC[ot][nt], 0, 0, 0);
        }
    }
  }

  // ---- epilogue: y = silu(hh + corr*2^-11 + bias) + emb -> xout ----
  // C/D layout: col = lane&15 (cell), row = (lane>>4)*4 + reg (oc).
  #pragma unroll
  for (int nt = 0; nt < 3; ++nt) {
    const int cell = (ntB + nt)*16 + lr;
    if (cell < 81) {
      float* xp = xout + ((size_t)b*81 + cell)*128;
      #pragma unroll
      for (int ot = 0; ot < 4; ++ot) {
        const int oc = (otB + ot)*16 + lg*4;
        const float4 b3 = *(const float4*)(c3_b + oc);
        const float4 e  = *(const float4*)(emb + cell*128 + oc);
        const f32x4 hh = accH[ot][nt];
        const f32x4 cc = accC[ot][nt];
        float4 o;
        o.x = silu_f(hh[0] + cc[0]*(1.f/2048.f) + b3.x) + e.x;
        o.y = silu_f(hh[1] + cc[1]*(1.f/2048.f) + b3.y) + e.y;
        o.z = silu_f(hh[2] + cc[2]*(1.f/2048.f) + b3.z) + e.z;
        o.w = silu_f(hh[3] + cc[3]*(1.f/2048.f) + b3.w) + e.w;
        *(float4*)(xp + oc) = o;
      }
    }
  }
}

// ---------------- attention ------------------------------------------------
// 512 threads / board. Dynamic LDS layout (floats):
//  xL   @ 0      [81][132]  staged board activations (row-major, k-contig)
//  qkT  @ 10692  [84][68]   q,k cell-major: qkT[cell][m], m 0..31 q, 32..63 k
//  vL   @ 16404  [32][84]   v row-major: vL[j][cell]
//  sc   @ 19092  [81][84]   scores -> probs (pad cols zeroed)
//  red  @ 25896  [486]      softmax partials
//  rmax @ 26544  [81]
//  rinv @ 26625  [81]
#define ATTN_LDS_BYTES (27392*4)

__global__ __launch_bounds__(512) void k_attn(
    const float* __restrict__ x, const float* __restrict__ in_w,
    const float* __restrict__ in_b, float* __restrict__ ctxg,
    float* __restrict__ asc)
{
  extern __shared__ float sm[];
  float* xL   = sm;
  float* qkT  = sm + 10692;
  float* vL   = sm + 16404;
  float* sc   = sm + 19092;
  float* red  = sm + 25896;
  float* rmax = sm + 26544;
  float* rinv = sm + 26625;

  const int b   = blockIdx.x;
  const int tid = threadIdx.x;
  const int rg  = tid >> 5;     // 0..15
  const int cg  = tid & 31;     // 0..31

  // stage x -> xL (coalesced global float4)
  {
    const float4* xg = (const float4*)(x + (size_t)b*81*128);
    for (int i = tid; i < 81*32; i += 512) {
      int n = i >> 5, k4 = i & 31;
      *(float4*)(xL + n*132 + k4*4) = xg[n*32 + k4];
    }
  }

  float ascR[13];
  #pragma unroll
  for (int i = 0; i < 13; ++i) ascR[i] = 0.f;

  __syncthreads();

  for (int h = 0; h < 4; ++h) {
    // ---- QKV: rows m = rg*6+i (0..95), cells n = cg + {0,32,64}
    {
      float acc[18];
      #pragma unroll
      for (int i = 0; i < 18; ++i) acc[i] = 0.f;
      int rows[6];
      #pragma unroll
      for (int i = 0; i < 6; ++i) {
        int m = rg*6 + i;
        rows[i] = (m < 32) ? (h*32 + m)
                : (m < 64) ? (128 + h*32 + (m - 32))
                           : (256 + h*32 + (m - 64));
      }
      const float* x0p = xL + cg*132;
      const float* x1p = xL + (cg+32)*132;
      const float* x2p = xL + (cg+64)*132;
      #pragma unroll 2
      for (int k4 = 0; k4 < 32; ++k4) {
        const int ko = k4*4;
        float4 x0 = *(const float4*)(x0p + ko);
        float4 x1 = *(const float4*)(x1p + ko);
        float4 x2 = *(const float4*)(x2p + ko);
        #pragma unroll
        for (int i = 0; i < 6; ++i) {
          float4 w = *(const float4*)(in_w + rows[i]*128 + ko);
          dacc(acc[i*3 + 0], w, x0);
          dacc(acc[i*3 + 1], w, x1);
          dacc(acc[i*3 + 2], w, x2);
        }
      }
      #pragma unroll
      for (int i = 0; i < 6; ++i) {
        const int m = rg*6 + i;
        const float bias = in_b[rows[i]];
        float s0 = acc[i*3 + 0] + bias;
        float s1 = acc[i*3 + 1] + bias;
        float s2 = acc[i*3 + 2] + bias;
        if (m < 64) {
          qkT[cg*68 + m]      = s0;
          qkT[(cg+32)*68 + m] = s1;
          if (cg+64 < 81) qkT[(cg+64)*68 + m] = s2;
        } else {
          const int j = m - 64;
          vL[j*84 + cg]      = s0;
          vL[j*84 + cg+32]   = s1;
          if (cg+64 < 81)      vL[j*84 + cg+64] = s2;
          else if (cg+64 < 84) vL[j*84 + cg+64] = 0.f;   // zero pad cols
        }
      }
    }
    __syncthreads();

    // ---- scores: q = rg*6+i, k = cg*3+jj, dot over m=32
    {
      float acc[18];
      #pragma unroll
      for (int i = 0; i < 18; ++i) acc[i] = 0.f;
      const int q0 = rg*6, kc0 = cg*3;
      #pragma unroll 2
      for (int m4 = 0; m4 < 8; ++m4) {
        const int mo = m4*4;
        float4 kv0 = *(const float4*)(qkT + (kc0+0)*68 + 32 + mo);
        float4 kv1 = *(const float4*)(qkT + (kc0+1)*68 + 32 + mo);
        float4 kv2 = *(const float4*)(qkT + (kc0+2)*68 + 32 + mo);
        #pragma unroll
        for (int i = 0; i < 6; ++i) {
          float4 qv = *(const float4*)(qkT + (q0+i)*68 + mo);
          dacc(acc[i*3 + 0], qv, kv0);
          dacc(acc[i*3 + 1], qv, kv1);
          dacc(acc[i*3 + 2], qv, kv2);
        }
      }
      #pragma unroll
      for (int i = 0; i < 6; ++i) {
        const int q = q0 + i;
        if (q < 81) {
          const int qrow = q/9, qcol = q - qrow*9;
          const int qbox = (qrow/3)*3 + qcol/3;
          #pragma unroll
          for (int jj = 0; jj < 3; ++jj) {
            const int k = kc0 + jj;
            if (k < 81) {
              const int krow = k/9, kcol = k - krow*9;
              const int kbox = (krow/3)*3 + kcol/3;
              float msk = (h==0) ? (qrow==krow ? 1.f : 0.f)
                        : (h==1) ? (qcol==kcol ? 1.f : 0.f)
                        : (h==2) ? (qbox==kbox ? 1.f : 0.f)
                                 : 1.f;
              sc[q*84 + k] = acc[i*3 + jj] / 5.656854249492381f + msk;
            }
          }
        }
      }
    }
    __syncthreads();

    // ---- softmax: 6 threads per row
    if (tid < 486) {
      const int r = tid / 6, j = tid - (tid/6)*6;
      const int kb = j*14;
      float m = -INFINITY;
      for (int c = 0; c < 14; ++c) {
        int k = kb + c;
        if (k < 81) m = fmaxf(m, sc[r*84 + k]);
      }
      red[tid] = m;
    }
    __syncthreads();
    if (tid < 81) {
      float m = red[tid*6];
      #pragma unroll
      for (int j = 1; j < 6; ++j) m = fmaxf(m, red[tid*6 + j]);
      rmax[tid] = m;
    }
    __syncthreads();
    if (tid < 486) {
      const int r = tid / 6, j = tid - (tid/6)*6;
      const int kb = j*14;
      const float m = rmax[r];
      float ssum = 0.f;
      for (int c = 0; c < 14; ++c) {
        int k = kb + c;
        if (k < 81) ssum += expf(sc[r*84 + k] - m);
      }
      red[tid] = ssum;
    }
    __syncthreads();
    if (tid < 81) {
      float ssum = 0.f;
      #pragma unroll
      for (int j = 0; j < 6; ++j) ssum += red[tid*6 + j];
      rinv[tid] = 1.0f / ssum;
      sc[tid*84 + 81] = 0.f; sc[tid*84 + 82] = 0.f; sc[tid*84 + 83] = 0.f;
    }
    __syncthreads();

    // ---- probs in place + asc register accumulation
    #pragma unroll
    for (int i = 0; i < 13; ++i) {
      const int idx = tid + i*512;
      if (idx < 6561) {
        const int q = idx / 81, k = idx - q*81;
        float a = expf(sc[q*84 + k] - rmax[q]) * rinv[q];
        sc[q*84 + k] = a;
        ascR[i] += a;
      }
    }
    __syncthreads();

    // ---- ctx: n = (tid&31)*3+{0,1,2}, j = (tid>>5)*2+{0,1}; dot over k
    {
      const int ng = tid & 31, jg = tid >> 5;
      const int nb = ng*3, jb = jg*2;
      float a00=0.f, a01=0.f, a10=0.f, a11=0.f, a20=0.f, a21=0.f;
      const float* v0p = vL + jb*84;
      const float* v1p = vL + (jb+1)*84;
      const float* p0p = sc + nb*84;
      const float* p1p = sc + (nb+1)*84;
      const float* p2p = sc + (nb+2)*84;
      #pragma unroll 2
      for (int k4 = 0; k4 < 21; ++k4) {
        const int ko = k4*4;
        float4 v0 = *(const float4*)(v0p + ko);
        float4 v1 = *(const float4*)(v1p + ko);
        float4 p0 = *(const float4*)(p0p + ko);
        float4 p1 = *(const float4*)(p1p + ko);
        float4 p2 = *(const float4*)(p2p + ko);
        dacc(a00, p0, v0); dacc(a01, p0, v1);
        dacc(a10, p1, v0); dacc(a11, p1, v1);
        dacc(a20, p2, v0); dacc(a21, p2, v1);
      }
      float* cb = ctxg + ((size_t)b*128 + h*32)*81;
      if (nb   < 81) { cb[jb*81 + nb]       = a00;
                       cb[(jb+1)*81 + nb]   = a01; }
      if (nb+1 < 81) { cb[jb*81 + nb+1]     = a10;
                       cb[(jb+1)*81 + nb+1] = a11; }
      if (nb+2 < 81) { cb[jb*81 + nb+2]     = a20;
                       cb[(jb+1)*81 + nb+2] = a21; }
    }
    __syncthreads();
  } // heads

  // asc = mean over heads, single coalesced write
  #pragma unroll
  for (int i = 0; i < 13; ++i) {
    const int idx = tid + i*512;
    if (idx < 6561) asc[(size_t)b*6561 + idx] = 0.25f * ascR[i];
  }
}

// ---------------- post: out-proj, LN, l1, l2, heads + sampling -------------
__global__ __launch_bounds__(256) void k_post(
    const float* __restrict__ ctxg,
    const float* __restrict__ owT,  const float* __restrict__ out_b,
    const float* __restrict__ ln_g, const float* __restrict__ ln_b,
    const float* __restrict__ l1T,  const float* __restrict__ l1_b,
    const float* __restrict__ l2T,  const float* __restrict__ l2_b,
    const float* __restrict__ pos_w, const float* __restrict__ pos_b,
    const float* __restrict__ num_w, const float* __restrict__ num_b,
    const int* __restrict__ digits,  float* __restrict__ dout)
{
  __shared__ float yT[128*84];
  __shared__ float red[243];
  __shared__ float mu[81], rstd[81];
  __shared__ float vals[81];
  __shared__ int   posIdx;
  const int b   = blockIdx.x;
  const int tid = threadIdx.x;
  const int ocg = tid >> 3;   // 0..31
  const int ng  = tid & 7;    // 0..7 (ng==7 idle in GEMMs)

  // stage ctx (global [b][128][81]) -> yT[k][n]; zero pad cols 81..83
  {
    const float* cb = ctxg + (size_t)b*128*81;
    for (int i = tid; i < 128*81; i += 256) {
      int k = i / 81, n = i - k*81;
      yT[k*84 + n] = cb[i];
    }
    for (int i = tid; i < 128*3; i += 256) {
      int k = i / 3, c = i - k*3;
      yT[k*84 + 81 + c] = 0.f;
    }
  }
  __syncthreads();

  // ---- out projection (reads yT as ctx, writes yT as y) ----
  {
    float4 acc[4][3];
    #pragma unroll
    for (int c = 0; c < 4; ++c)
      { acc[c][0]=zero4(); acc[c][1]=zero4(); acc[c][2]=zero4(); }
    if (ng < 7) {
      #pragma unroll 2
      for (int k = 0; k < 128; ++k) {
        const float4 wv = *(const float4*)(owT + k*128 + ocg*4);
        const float* yr = yT + k*84 + ng*12;
        float4 x0 = *(const float4*)(yr);
        float4 x1 = *(const float4*)(yr + 4);
        float4 x2 = *(const float4*)(yr + 8);
        fma4b(acc[0][0], wv.x, x0); fma4b(acc[0][1], wv.x, x1); fma4b(acc[0][2], wv.x, x2);
        fma4b(acc[1][0], wv.y, x0); fma4b(acc[1][1], wv.y, x1); fma4b(acc[1][2], wv.y, x2);
        fma4b(acc[2][0], wv.z, x0); fma4b(acc[2][1], wv.z, x1); fma4b(acc[2][2], wv.z, x2);
        fma4b(acc[3][0], wv.w, x0); fma4b(acc[3][1], wv.w, x1); fma4b(acc[3][2], wv.w, x2);
      }
    }
    __syncthreads();
    if (ng < 7) {
      #pragma unroll
      for (int c = 0; c < 4; ++c) {
        const float bv = out_b[ocg*4 + c];
        #pragma unroll
        for (int t = 0; t < 3; ++t) {
          float4 o = acc[c][t];
          o.x += bv; o.y += bv; o.z += bv; o.w += bv;
          *(float4*)(yT + (ocg*4 + c)*84 + ng*12 + t*4) = o;
        }
      }
    }
  }
  __syncthreads();

  // ---- LayerNorm over k (columns n) ----
  if (tid < 243) {
    const int n = tid/3, j = tid - (tid/3)*3;
    float ssum = 0.f;
    for (int c = 0; c < 43; ++c) {
      int k = j*43 + c;
      if (k < 128) ssum += yT[k*84 + n];
    }
    red[tid] = ssum;
  }
  __syncthreads();
  if (tid < 81)
    mu[tid] = (red[tid*3] + red[tid*3+1] + red[tid*3+2]) * (1.0f/128.0f);
  __syncthreads();
  if (tid < 243) {
    const int n = tid/3, j = tid - (tid/3)*3;
    const float m = mu[n];
    float ssum = 0.f;
    for (int c = 0; c < 43; ++c) {
      int k = j*43 + c;
      if (k < 128) { float d = yT[k*84 + n] - m; ssum += d*d; }
    }
    red[tid] = ssum;
  }
  __syncthreads();
  if (tid < 81) {
    float v = (red[tid*3] + red[tid*3+1] + red[tid*3+2]) * (1.0f/128.0f);
    rstd[tid] = 1.0f / sqrtf(v + 1e-5f);
  }
  __syncthreads();
  for (int i = tid; i < 128*81; i += 256) {
    const int k = i / 81, n = i - k*81;
    yT[k*84 + n] = (yT[k*84 + n] - mu[n]) * rstd[n] * ln_g[k] + ln_b[k];
  }
  __syncthreads();

  // ---- l1 (silu) ----
  {
    float4 acc[4][3];
    #pragma unroll
    for (int c = 0; c < 4; ++c)
      { acc[c][0]=zero4(); acc[c][1]=zero4(); acc[c][2]=zero4(); }
    if (ng < 7) {
      #pragma unroll 2
      for (int k = 0; k < 128; ++k) {
        const float4 wv = *(const float4*)(l1T + k*128 + ocg*4);
        const float* yr = yT + k*84 + ng*12;
        float4 x0 = *(const float4*)(yr);
        float4 x1 = *(const float4*)(yr + 4);
        float4 x2 = *(const float4*)(yr + 8);
        fma4b(acc[0][0], wv.x, x0); fma4b(acc[0][1], wv.x, x1); fma4b(acc[0][2], wv.x, x2);
        fma4b(acc[1][0], wv.y, x0); fma4b(acc[1][1], wv.y, x1); fma4b(acc[1][2], wv.y, x2);
        fma4b(acc[2][0], wv.z, x0); fma4b(acc[2][1], wv.z, x1); fma4b(acc[2][2], wv.z, x2);
        fma4b(acc[3][0], wv.w, x0); fma4b(acc[3][1], wv.w, x1); fma4b(acc[3][2], wv.w, x2);
      }
    }
    __syncthreads();
    if (ng < 7) {
      #pragma unroll
      for (int c = 0; c < 4; ++c) {
        const float bv = l1_b[ocg*4 + c];
        #pragma unroll
        for (int t = 0; t < 3; ++t) {
          float4 o = acc[c][t];
          o.x = silu_f(o.x + bv); o.y = silu_f(o.y + bv);
          o.z = silu_f(o.z + bv); o.w = silu_f(o.w + bv);
          *(float4*)(yT + (ocg*4 + c)*84 + ng*12 + t*4) = o;
        }
      }
    }
  }
  __syncthreads();

  // ---- l2 (silu) ----
  {
    float4 acc[4][3];
    #pragma unroll
    for (int c = 0; c < 4; ++c)
      { acc[c][0]=zero4(); acc[c][1]=zero4(); acc[c][2]=zero4(); }
    if (ng < 7) {
      #pragma unroll 2
      for (int k = 0; k < 128; ++k) {
        const float4 wv = *(const float4*)(l2T + k*128 + ocg*4);
        const float* yr = yT + k*84 + ng*12;
        float4 x0 = *(const float4*)(yr);
        float4 x1 = *(const float4*)(yr + 4);
        float4 x2 = *(const float4*)(yr + 8);
        fma4b(acc[0][0], wv.x, x0); fma4b(acc[0][1], wv.x, x1); fma4b(acc[0][2], wv.x, x2);
        fma4b(acc[1][0], wv.y, x0); fma4b(acc[1][1], wv.y, x1); fma4b(acc[1][2], wv.y, x2);
        fma4b(acc[2][0], wv.z, x0); fma4b(acc[2][1], wv.z, x1); fma4b(acc[2][2], wv.z, x2);
        fma4b(acc[3][0], wv.w, x0); fma4b(acc[3][1], wv.w, x1); fma4b(acc[3][2], wv.w, x2);
      }
    }
    __syncthreads();
    if (ng < 7) {
      #pragma unroll
      for (int c = 0; c < 4; ++c) {
        const float bv = l2_b[ocg*4 + c];
        #pragma unroll
        for (int t = 0; t < 3; ++t) {
          float4 o = acc[c][t];
          o.x = silu_f(o.x + bv); o.y = silu_f(o.y + bv);
          o.z = silu_f(o.z + bv); o.w = silu_f(o.w + bv);
          *(float4*)(yT + (ocg*4 + c)*84 + ng*12 + t*4) = o;
        }
      }
    }
  }
  __syncthreads();

  // ---- position head + gumbel sampling ----
  uint32_t k1a, k1b, k2a, k2b;
  jax_split42(k1a, k1b, k2a, k2b);

  if (tid < 243) {
    const int n = tid/3, j = tid - (tid/3)*3;
    float ssum = 0.f;
    for (int c = 0; c < 43; ++c) {
      int k = j*43 + c;
      if (k < 128) ssum += yT[k*84 + n] * pos_w[k];
    }
    red[tid] = ssum;
  }
  __syncthreads();
  if (tid < 81) {
    float acc = red[tid*3] + red[tid*3+1] + red[tid*3+2] + pos_b[0];
    if (digits[b*81 + tid] != 0) acc = -1e9f;
    uint32_t bits = jax_randbits(k1a, k1b, (uint32_t)(b*81 + tid));
    vals[tid] = acc + jax_gumbel_bits(bits);
  }
  __syncthreads();
  if (tid == 0) {
    float best = vals[0]; int bi = 0;
    for (int n = 1; n < 81; ++n)
      if (vals[n] > best) { best = vals[n]; bi = n; }
    posIdx = bi;
    dout[b] = (float)bi;
  }
  __syncthreads();
  const int pos = posIdx;

  // ---- number head at sampled position ----
  if (tid < 80) {
    const int d = tid >> 3, j = tid & 7;
    float ssum = 0.f;
    #pragma unroll
    for (int c = 0; c < 16; ++c) {
      int k = j*16 + c;
      ssum += yT[k*84 + pos] * num_w[d*128 + k];
    }
    red[tid] = ssum;
  }
  __syncthreads();
  if (tid < 10) {
    float acc = num_b[tid];
    #pragma unroll
    for (int j = 0; j < 8; ++j) acc += red[tid*8 + j];
    if (tid == 0) acc = -INFINITY;
    uint32_t bits = jax_randbits(k2a, k2b, (uint32_t)(b*10 + tid));
    vals[tid] = acc + jax_gumbel_bits(bits);
  }
  __syncthreads();
  if (tid == 0) {
    float best = vals[0]; int bi = 0;
    for (int d = 1; d < 10; ++d)
      if (vals[d] > best) { best = vals[d]; bi = d; }
    dout[NB + b] = (float)bi;
  }
}

// ---------------------------------------------------------------------------
extern "C" void kernel_launch(void* const* d_in, const int* in_sizes, int n_in,
                              void* d_out, int out_size, void* d_ws, size_t ws_size,
                              hipStream_t stream) {
  const float* s     = (const float*)d_in[0];
  const float* c1_w  = (const float*)d_in[1];
  const float* c1_b  = (const float*)d_in[2];
  const float* c2_w  = (const float*)d_in[3];
  const float* c2_b  = (const float*)d_in[4];
  const float* c3_w  = (const float*)d_in[5];
  const float* c3_b  = (const float*)d_in[6];
  const float* emb   = (const float*)d_in[7];
  const float* in_w  = (const float*)d_in[8];
  const float* in_b  = (const float*)d_in[9];
  const float* out_w = (const float*)d_in[10];
  const float* out_b = (const float*)d_in[11];
  const float* ln_g  = (const float*)d_in[12];
  const float* ln_b  = (const float*)d_in[13];
  const float* l1_w  = (const float*)d_in[14];
  const float* l1_b  = (const float*)d_in[15];
  const float* l2_w  = (const float*)d_in[16];
  const float* l2_b  = (const float*)d_in[17];
  const float* pos_w = (const float*)d_in[18];
  const float* pos_b = (const float*)d_in[19];
  const float* num_w = (const float*)d_in[20];
  const float* num_b = (const float*)d_in[21];

  // ws layout (floats):
  // T2e 0 (12672) | WAh 12672 (73728 f = 147456 u16) | WAl 86400 (73728 f) |
  // owT 160128 (16384) | l1T 176512 (16384) | l2T 192896 (16384) |
  // digits 209280 (331776 int) | x 541056 (42467328) | ctxg 43008384
  float* ws     = (float*)d_ws;
  float* T2e    = ws;
  u16*   WAh    = (u16*)(ws + 12672);
  u16*   WAl    = (u16*)(ws + 86400);
  float* owT    = ws + 160128;
  float* l1T    = ws + 176512;
  float* l2T    = ws + 192896;
  int*   digits = (int*)(ws + 209280);
  float* x      = ws + 541056;
  float* ctxg   = ws + 43008384;

  float* dout = (float*)d_out;
  float* asc  = dout + 2*NB;

  hipFuncSetAttribute((const void*)k_attn,
                      hipFuncAttributeMaxDynamicSharedMemorySize,
                      ATTN_LDS_BYTES);

  k_prep<<<dim3(818), dim3(256), 0, stream>>>(
      c1_w, c1_b, c2_w, c3_w, out_w, l1_w, l2_w,
      T2e, WAh, WAl, owT, l1T, l2T);
  k_stem<<<dim3(NB), dim3(256), 0, stream>>>(
      s, T2e, c2_b, WAh, WAl, c3_b, emb, x, digits);
  k_attn<<<dim3(NB), dim3(512), ATTN_LDS_BYTES, stream>>>(
      x, in_w, in_b, ctxg, asc);
  k_post<<<dim3(NB), dim3(256), 0, stream>>>(
      ctxg, owT, out_b, ln_g, ln_b, l1T, l1_b, l2T, l2_b,
      pos_w, pos_b, num_w, num_b, digits, dout);
}

// Round 2
// 1862.300 us; speedup vs baseline: 2.6881x; 1.7335x over previous
//
#include <hip/hip_runtime.h>
#include <stdint.h>
#include <math.h>

// ---------------------------------------------------------------------------
// p_net forward on MI355X.  B=4096 boards, N=81 cells, D=128, H=4 heads.
// Round 8: k_attn moved to MFMA (mfma_f32_16x16x32_f16) with split-fp16
// precision (hi + lo*2^-11) for QKV projection, scores, and PV — same
// scheme already validated in k_stem. x, q/k, vT, P staged in XOR-swizzled
// LDS (slot ^= row&7) for conflict-free ds_read_b128 fragments. P converted
// f32->fp16 hi/lo in place (aliases score buffer); asc taken from f32 probs
// before conversion so its precision is unchanged.
// Outputs (concat, float32): pos[4096], num[4096], asc[4096*81*81].
// ---------------------------------------------------------------------------

#define NB 4096

typedef unsigned short u16;
typedef _Float16 f16x8 __attribute__((ext_vector_type(8)));
typedef float f32x4 __attribute__((ext_vector_type(4)));

__device__ __forceinline__ float silu_f(float v) {
  return v / (1.0f + expf(-v));
}

__device__ __forceinline__ float4 zero4() { return make_float4(0.f,0.f,0.f,0.f); }

__device__ __forceinline__ void fma4b(float4& a, const float s, const float4 x) {
  a.x = fmaf(s, x.x, a.x); a.y = fmaf(s, x.y, a.y);
  a.z = fmaf(s, x.z, a.z); a.w = fmaf(s, x.w, a.w);
}

// sequential dot-accumulate: a += w·x, 4 fmaf, scalar accumulator
__device__ __forceinline__ void dacc(float& a, const float4 w, const float4 x) {
  a = fmaf(w.x, x.x, a); a = fmaf(w.y, x.y, a);
  a = fmaf(w.z, x.z, a); a = fmaf(w.w, x.w, a);
}

// split fp32 -> fp16 hi + fp16 lo (lo scaled by 2^11 to dodge denormals)
__device__ __forceinline__ void splitu(float v, u16& h, u16& l) {
  _Float16 hf = (_Float16)v;
  _Float16 lf = (_Float16)((v - (float)hf) * 2048.0f);
  union { _Float16 f; u16 u; } a, b;
  a.f = hf; b.f = lf;
  h = a.u; l = b.u;
}

// ---------------- Threefry-2x32 (JAX partitionable) ------------------------
__device__ __forceinline__ void tf_round(uint32_t& x0, uint32_t& x1, int r) {
  x0 += x1;
  x1 = (x1 << r) | (x1 >> (32 - r));
  x1 ^= x0;
}

__device__ __forceinline__ void threefry2x32(uint32_t k0, uint32_t k1,
                                             uint32_t x0, uint32_t x1,
                                             uint32_t& o0, uint32_t& o1) {
  uint32_t k2 = k0 ^ k1 ^ 0x1BD11BDAu;
  x0 += k0; x1 += k1;
  tf_round(x0,x1,13); tf_round(x0,x1,15); tf_round(x0,x1,26); tf_round(x0,x1,6);
  x0 += k1; x1 += k2 + 1u;
  tf_round(x0,x1,17); tf_round(x0,x1,29); tf_round(x0,x1,16); tf_round(x0,x1,24);
  x0 += k2; x1 += k0 + 2u;
  tf_round(x0,x1,13); tf_round(x0,x1,15); tf_round(x0,x1,26); tf_round(x0,x1,6);
  x0 += k0; x1 += k1 + 3u;
  tf_round(x0,x1,17); tf_round(x0,x1,29); tf_round(x0,x1,16); tf_round(x0,x1,24);
  x0 += k1; x1 += k2 + 4u;
  tf_round(x0,x1,13); tf_round(x0,x1,15); tf_round(x0,x1,26); tf_round(x0,x1,6);
  x0 += k2; x1 += k0 + 5u;
  o0 = x0; o1 = x1;
}

__device__ __forceinline__ void jax_split42(uint32_t& k1a, uint32_t& k1b,
                                            uint32_t& k2a, uint32_t& k2b) {
  threefry2x32(0u, 42u, 0u, 0u, k1a, k1b);
  threefry2x32(0u, 42u, 0u, 1u, k2a, k2b);
}

__device__ __forceinline__ uint32_t jax_randbits(uint32_t ka, uint32_t kb,
                                                 uint32_t i) {
  uint32_t o0, o1;
  threefry2x32(ka, kb, 0u, i, o0, o1);
  return o0 ^ o1;
}

__device__ __forceinline__ float jax_gumbel_bits(uint32_t bits) {
  float f = __uint_as_float((bits >> 9) | 0x3f800000u) - 1.0f;
  const float tiny = 1.17549435e-38f;
  float u = fmaxf(tiny, f + tiny);
  return -logf(-logf(u));
}

// ---------------- prep: conv tables + fragment-packed conv3 weights --------
// WAh/WAl layout: [(d*4 + kc)*8 + ot][lane 0..63][j 0..7] fp16 bits.
// Fragment semantics: A[m][k], m = lane&15 (oc within 16-tile),
// k-slot = (lane>>4)*8 + j  -> ic = kc*32 + (lane>>4)*8 + j.
__global__ __launch_bounds__(256) void k_prep(
    const float* __restrict__ c1_w, const float* __restrict__ c1_b,
    const float* __restrict__ c2_w, const float* __restrict__ c3_w,
    const float* __restrict__ out_w, const float* __restrict__ l1_w,
    const float* __restrict__ l2_w,
    float* __restrict__ T2e, u16* __restrict__ WAh, u16* __restrict__ WAl,
    float* __restrict__ owT, float* __restrict__ l1T, float* __restrict__ l2T)
{
  int idx = blockIdx.x * 256 + threadIdx.x;
  if (idx < 9*11*128) {
    int oc = idx & 127;
    int t  = idx >> 7;
    int g  = t % 11;
    int d  = t / 11;
    float acc = 0.f;
    if (g < 10) {
      int di = d / 3, dj = d % 3;
      for (int ic = 0; ic < 64; ++ic) {
        float x1 = c1_w[ic*10 + g] + c1_b[ic];
        acc += c2_w[((oc*64 + ic)*3 + di)*3 + dj] * x1;
      }
    }
    T2e[idx] = acc;
  } else if (idx < 160128) {
    int j  = idx - 12672;          // 0..147455
    int jj = j & 7;
    int t  = j >> 3;               // ((d*4+kc)*8+ot)*64 + lane
    int ln = t & 63;
    int t2 = t >> 6;               // (d*4+kc)*8 + ot
    int ot = t2 & 7;
    int t3 = t2 >> 3;              // d*4 + kc
    int kc = t3 & 3;
    int d  = t3 >> 2;
    int oc = ot*16 + (ln & 15);
    int ic = kc*32 + (ln >> 4)*8 + jj;
    float w = c3_w[(oc*128 + ic)*9 + d];
    u16 wh, wl;
    splitu(w, wh, wl);
    WAh[j] = wh; WAl[j] = wl;
  } else if (idx < 176512) {
    int j = idx - 160128;                      // j = k*128 + oc
    owT[j] = out_w[(j & 127)*128 + (j >> 7)];
  } else if (idx < 192896) {
    int j = idx - 176512;
    l1T[j] = l1_w[(j & 127)*128 + (j >> 7)];
  } else if (idx < 209280) {
    int j = idx - 192896;
    l2T[j] = l2_w[(j & 127)*128 + (j >> 7)];
  }
}

// ---------------- stem: digits -> conv2(table, fp16 hi/lo in LDS)
//                  -> conv3 on MFMA (split-fp16) -> +emb -------------------
// 256 threads (4 waves) / board. LDS: x2h/x2l [121 rows][128 ch] fp16,
// XOR-swizzled within row: byte ^= ((row&7)<<4). Pad rows are zero.
__global__ __launch_bounds__(256, 2) void k_stem(
    const float* __restrict__ s, const float* __restrict__ T2e,
    const float* __restrict__ c2_b,
    const u16* __restrict__ WAh, const u16* __restrict__ WAl,
    const float* __restrict__ c3_b, const float* __restrict__ emb,
    float* __restrict__ xout, int* __restrict__ digits)
{
  __shared__ __align__(16) u16 x2h[121*128];   // 30976 B
  __shared__ __align__(16) u16 x2l[121*128];   // 30976 B
  __shared__ int dg[121];                      // padded digit grid, 10 = pad
  const int b   = blockIdx.x;
  const int tid = threadIdx.x;

  // zero-fill activation buffers (pad rows must stay zero) + dg sentinel
  for (int i = tid; i < 1936; i += 256) {
    ((uint4*)x2h)[i] = make_uint4(0u,0u,0u,0u);
    ((uint4*)x2l)[i] = make_uint4(0u,0u,0u,0u);
  }
  if (tid < 121) dg[tid] = 10;
  __syncthreads();

  if (tid < 81) {
    const float* sp = s + (size_t)b*810 + tid;
    float dv = 0.f;
    #pragma unroll
    for (int c = 1; c < 10; ++c) dv += (float)c * sp[c*81];
    int d = (int)(dv + 0.5f);
    dg[(tid/9 + 1)*11 + (tid%9 + 1)] = d;
    digits[b*81 + tid] = d;
  }
  __syncthreads();

  // ---- conv2 via table: 81 cells x 16 chunks of 8 channels ----
  for (int i = tid; i < 1296; i += 256) {
    const int p  = i >> 4;          // 0..80
    const int k8 = i & 15;          // channel chunk
    const int r0 = p / 9, c0 = p - r0*9;
    const float4 b0 = *(const float4*)(c2_b + k8*8);
    const float4 b1 = *(const float4*)(c2_b + k8*8 + 4);
    float a0=b0.x, a1=b0.y, a2=b0.z, a3=b0.w;
    float a4=b1.x, a5=b1.y, a6=b1.z, a7=b1.w;
    #pragma unroll
    for (int d = 0; d < 9; ++d) {
      const int g = dg[(r0 + d/3)*11 + (c0 + d%3)];
      const float* tp = T2e + (size_t)(d*11 + g)*128 + k8*8;
      const float4 t0 = *(const float4*)tp;
      const float4 t1 = *(const float4*)(tp + 4);
      a0 += t0.x; a1 += t0.y; a2 += t0.z; a3 += t0.w;
      a4 += t1.x; a5 += t1.y; a6 += t1.z; a7 += t1.w;
    }
    float v[8];
    v[0]=silu_f(a0); v[1]=silu_f(a1); v[2]=silu_f(a2); v[3]=silu_f(a3);
    v[4]=silu_f(a4); v[5]=silu_f(a5); v[6]=silu_f(a6); v[7]=silu_f(a7);
    f16x8 hv, lv;
    #pragma unroll
    for (int j = 0; j < 8; ++j) {
      _Float16 h = (_Float16)v[j];
      hv[j] = h;
      lv[j] = (_Float16)((v[j] - (float)h) * 2048.0f);
    }
    const int row = (r0 + 1)*11 + (c0 + 1);
    const uint32_t bo = (uint32_t)row*256u + (uint32_t)((k8*16) ^ ((row & 7) << 4));
    *(f16x8*)((char*)x2h + bo) = hv;
    *(f16x8*)((char*)x2l + bo) = lv;
  }
  __syncthreads();

  // ---- conv3 on MFMA: D[128 oc][96 cells] = sum_d W_d · x2(shifted) ----
  // 48 tiles (8 octiles x 6 ntiles); wave owns 4 octiles x 3 ntiles.
  const int ln  = tid & 63;
  const int wv  = tid >> 6;
  const int lg  = ln >> 4;          // lane group 0..3
  const int lr  = ln & 15;
  const int otB = (wv & 1) * 4;     // octile base
  const int ntB = (wv >> 1) * 3;    // ntile base

  f32x4 accH[4][3];
  f32x4 accC[4][3];
  #pragma unroll
  for (int ot = 0; ot < 4; ++ot)
    #pragma unroll
    for (int nt = 0; nt < 3; ++nt) {
      accH[ot][nt] = (f32x4){0.f,0.f,0.f,0.f};
      accC[ot][nt] = (f32x4){0.f,0.f,0.f,0.f};
    }

  int pbase[3];
  #pragma unroll
  for (int nt = 0; nt < 3; ++nt) {
    const int c = (ntB + nt)*16 + lr;
    pbase[nt] = (c < 81) ? (c/9)*11 + (c%9) : 0;   // invalid lanes -> cell 0 (unstored)
  }
  const char* x2hB = (const char*)x2h;
  const char* x2lB = (const char*)x2l;

  for (int d = 0; d < 9; ++d) {
    const int off = (d/3)*11 + (d - (d/3)*3);
    int rowv[3];
    #pragma unroll
    for (int nt = 0; nt < 3; ++nt) rowv[nt] = pbase[nt] + off;
    #pragma unroll
    for (int kc = 0; kc < 4; ++kc) {
      const int kb = kc*64 + lg*16;
      f16x8 Bh[3], Bl[3];
      #pragma unroll
      for (int nt = 0; nt < 3; ++nt) {
        const uint32_t o = (uint32_t)rowv[nt]*256u +
                           (uint32_t)(kb ^ ((rowv[nt] & 7) << 4));
        Bh[nt] = *(const f16x8*)(x2hB + o);
        Bl[nt] = *(const f16x8*)(x2lB + o);
      }
      const int abase = (((d*4 + kc)*8 + otB)*64 + ln)*8;
      f16x8 Ah[4], Al[4];
      #pragma unroll
      for (int ot = 0; ot < 4; ++ot) {
        Ah[ot] = *(const f16x8*)(WAh + abase + ot*512);
        Al[ot] = *(const f16x8*)(WAl + abase + ot*512);
      }
      #pragma unroll
      for (int ot = 0; ot < 4; ++ot)
        #pragma unroll
        for (int nt = 0; nt < 3; ++nt) {
          accH[ot][nt] = __builtin_amdgcn_mfma_f32_16x16x32_f16(
              Ah[ot], Bh[nt], accH[ot][nt], 0, 0, 0);
          accC[ot][nt] = __builtin_amdgcn_mfma_f32_16x16x32_f16(
              Ah[ot], Bl[nt], accC[ot][nt], 0, 0, 0);
          accC[ot][nt] = __builtin_amdgcn_mfma_f32_16x16x32_f16(
              Al[ot], Bh[nt], accC[ot][nt], 0, 0, 0);
        }
    }
  }

  // ---- epilogue: y = silu(hh + corr*2^-11 + bias) + emb -> xout ----
  // C/D layout: col = lane&15 (cell), row = (lane>>4)*4 + reg (oc).
  #pragma unroll
  for (int nt = 0; nt < 3; ++nt) {
    const int cell = (ntB + nt)*16 + lr;
    if (cell < 81) {
      float* xp = xout + ((size_t)b*81 + cell)*128;
      #pragma unroll
      for (int ot = 0; ot < 4; ++ot) {
        const int oc = (otB + ot)*16 + lg*4;
        const float4 b3 = *(const float4*)(c3_b + oc);
        const float4 e  = *(const float4*)(emb + cell*128 + oc);
        const f32x4 hh = accH[ot][nt];
        const f32x4 cc = accC[ot][nt];
        float4 o;
        o.x = silu_f(hh[0] + cc[0]*(1.f/2048.f) + b3.x) + e.x;
        o.y = silu_f(hh[1] + cc[1]*(1.f/2048.f) + b3.y) + e.y;
        o.z = silu_f(hh[2] + cc[2]*(1.f/2048.f) + b3.z) + e.z;
        o.w = silu_f(hh[3] + cc[3]*(1.f/2048.f) + b3.w) + e.w;
        *(float4*)(xp + oc) = o;
      }
    }
  }
}

// ---------------- attention (MFMA, split-fp16) -----------------------------
// 512 threads (8 waves) / board. LDS byte layout (all XOR-swizzled by
// slot ^= row&7 at 16B granularity):
//  XH/XL   @ 0 / 24576     [96 cells][128 ch] fp16 (stride 256B)
//  QKH/QKL @ 49152 / 61440 [96 cells][64]     q cols 0-31, k cols 32-63 (128B)
//  VTH/VTL @ 73728 / 81920 [32 hd][96+pad]    (stride 256B)
//  SC      @ 90112         f32 [96][132] scores -> exp; aliased after
//                          softmax by PH (24576B) + PL (24576B) fp16 probs
//  RED     @ 140800        [486] f32
//  RMAX    @ 142744  RINV @ 143068   [81] f32 each
#define ATTN_LDS_BYTES 143392

__global__ __launch_bounds__(512, 1) void k_attn(
    const float* __restrict__ x, const float* __restrict__ in_w,
    const float* __restrict__ in_b, float* __restrict__ ctxg,
    float* __restrict__ asc)
{
  extern __shared__ char smc[];
  char* XH  = smc;
  char* XL  = smc + 24576;
  char* QKH = smc + 49152;
  char* QKL = smc + 61440;
  char* VTH = smc + 73728;
  char* VTL = smc + 81920;
  float* SC = (float*)(smc + 90112);   // [96][132]
  char* PH  = smc + 90112;
  char* PL  = smc + 114688;
  float* RED  = (float*)(smc + 140800);
  float* RMAX = (float*)(smc + 142744);
  float* RINV = (float*)(smc + 143068);

  const int b   = blockIdx.x;
  const int tid = threadIdx.x;
  const int ln  = tid & 63;
  const int wv  = tid >> 6;     // wave 0..7
  const int lg  = ln >> 4;      // lane group 0..3
  const int lr  = ln & 15;

  // zero x buffers (pad cells 81-95 must be finite) then stage x as hi/lo
  for (int i = tid; i < 1536; i += 512) {
    ((uint4*)XH)[i] = make_uint4(0u,0u,0u,0u);
    ((uint4*)XL)[i] = make_uint4(0u,0u,0u,0u);
  }
  __syncthreads();
  {
    const float4* xg = (const float4*)(x + (size_t)b*81*128);
    for (int i = tid; i < 2592; i += 512) {
      const int n = i >> 5, k4 = i & 31;
      const float4 v = xg[i];
      ushort4 hv, lv;
      splitu(v.x, hv.x, lv.x); splitu(v.y, hv.y, lv.y);
      splitu(v.z, hv.z, lv.z); splitu(v.w, hv.w, lv.w);
      const uint32_t bo = (uint32_t)n*256u +
          (uint32_t)((((k4 >> 1) ^ (n & 7)) << 4) + (k4 & 1)*8);
      *(ushort4*)(XH + bo) = hv;
      *(ushort4*)(XL + bo) = lv;
    }
  }

  float ascR[21];
  #pragma unroll
  for (int i = 0; i < 21; ++i) ascR[i] = 0.f;

  __syncthreads();

  for (int h = 0; h < 4; ++h) {
    // ---- QKV: waves 0-5 each own one 16-row otile (q/k/v x 2 halves) ----
    if (wv < 6) {
      const int part = wv >> 1;          // 0=q 1=k 2=v
      const int sub  = wv & 1;           // 16-row half
      const int rowbase = part*128 + h*32 + sub*16;
      f32x4 accH[6], accC[6];
      #pragma unroll
      for (int nt = 0; nt < 6; ++nt) {
        accH[nt] = (f32x4){0.f,0.f,0.f,0.f};
        accC[nt] = (f32x4){0.f,0.f,0.f,0.f};
      }
      for (int kc = 0; kc < 4; ++kc) {
        // A fragment from in_w (on-the-fly hi/lo split), reused over 6 ntiles
        const float* wp = in_w + (size_t)(rowbase + lr)*128 + kc*32 + lg*8;
        f16x8 Ah, Al;
        #pragma unroll
        for (int j = 0; j < 8; ++j) {
          const float wvv = wp[j];
          const _Float16 hh = (_Float16)wvv;
          Ah[j] = hh;
          Al[j] = (_Float16)((wvv - (float)hh) * 2048.0f);
        }
        const uint32_t slotb = (uint32_t)(kc*4 + lg);
        #pragma unroll
        for (int nt = 0; nt < 6; ++nt) {
          const int row = nt*16 + lr;
          const uint32_t o = (uint32_t)row*256u + (((slotb ^ (row & 7))) << 4);
          const f16x8 Bh = *(const f16x8*)(XH + o);
          const f16x8 Bl = *(const f16x8*)(XL + o);
          accH[nt] = __builtin_amdgcn_mfma_f32_16x16x32_f16(Ah, Bh, accH[nt], 0,0,0);
          accC[nt] = __builtin_amdgcn_mfma_f32_16x16x32_f16(Ah, Bl, accC[nt], 0,0,0);
          accC[nt] = __builtin_amdgcn_mfma_f32_16x16x32_f16(Al, Bh, accC[nt], 0,0,0);
        }
      }
      // epilogue: + bias, split hi/lo, write q/k -> QK, v -> VT
      const float4 bia = *(const float4*)(in_b + rowbase + lg*4);
      #pragma unroll
      for (int nt = 0; nt < 6; ++nt) {
        const int cell = nt*16 + lr;
        float vv[4];
        vv[0] = accH[nt][0] + accC[nt][0]*(1.f/2048.f) + bia.x;
        vv[1] = accH[nt][1] + accC[nt][1]*(1.f/2048.f) + bia.y;
        vv[2] = accH[nt][2] + accC[nt][2]*(1.f/2048.f) + bia.z;
        vv[3] = accH[nt][3] + accC[nt][3]*(1.f/2048.f) + bia.w;
        if (part < 2) {
          ushort4 hw, lw;
          splitu(vv[0], hw.x, lw.x); splitu(vv[1], hw.y, lw.y);
          splitu(vv[2], hw.z, lw.z); splitu(vv[3], hw.w, lw.w);
          const uint32_t b0 = (uint32_t)(part*64 + sub*32 + lg*8);
          const uint32_t ad = (uint32_t)cell*128u +
              ((((b0 >> 4) ^ (cell & 7))) << 4) + (b0 & 15);
          *(ushort4*)(QKH + ad) = hw;
          *(ushort4*)(QKL + ad) = lw;
        } else {
          #pragma unroll
          for (int r = 0; r < 4; ++r) {
            const int hd = sub*16 + lg*4 + r;
            u16 hh, llv;
            splitu(vv[r], hh, llv);
            const uint32_t ad = (uint32_t)hd*256u +
                ((((cell >> 3) ^ (hd & 7))) << 4) + (cell & 7)*2;
            *(u16*)(VTH + ad) = hh;
            *(u16*)(VTL + ad) = llv;
          }
        }
      }
    }
    __syncthreads();

    // ---- scores: 36 tiles (6 qt x 6 nt), split over 8 waves ----
    {
      const int t0 = (wv*36) >> 3, t1 = ((wv + 1)*36) >> 3;
      for (int t = t0; t < t1; ++t) {
        const int qt = t/6, nt = t - qt*6;
        const int ra = qt*16 + lr;
        const uint32_t oa = (uint32_t)ra*128u + (((lg ^ (ra & 7))) << 4);
        const f16x8 Qh = *(const f16x8*)(QKH + oa);
        const f16x8 Ql = *(const f16x8*)(QKL + oa);
        const int rb = nt*16 + lr;
        const uint32_t ob = (uint32_t)rb*128u + ((((4 + lg) ^ (rb & 7))) << 4);
        const f16x8 Kh = *(const f16x8*)(QKH + ob);
        const f16x8 Kl = *(const f16x8*)(QKL + ob);
        f32x4 aH = (f32x4){0.f,0.f,0.f,0.f};
        f32x4 aC = (f32x4){0.f,0.f,0.f,0.f};
        aH = __builtin_amdgcn_mfma_f32_16x16x32_f16(Qh, Kh, aH, 0,0,0);
        aC = __builtin_amdgcn_mfma_f32_16x16x32_f16(Qh, Kl, aC, 0,0,0);
        aC = __builtin_amdgcn_mfma_f32_16x16x32_f16(Ql, Kh, aC, 0,0,0);
        const int kcell = nt*16 + lr;
        const int krow = kcell/9, kcol = kcell - krow*9;
        const int kbox = (krow/3)*3 + kcol/3;
        #pragma unroll
        for (int r = 0; r < 4; ++r) {
          const int q = qt*16 + lg*4 + r;
          const int qrow = q/9, qcol = q - qrow*9;
          const int qbox = (qrow/3)*3 + qcol/3;
          const float msk = (h==0) ? (qrow==krow ? 1.f : 0.f)
                          : (h==1) ? (qcol==kcol ? 1.f : 0.f)
                          : (h==2) ? (qbox==kbox ? 1.f : 0.f)
                                   : 1.f;
          SC[q*132 + kcell] =
              (aH[r] + aC[r]*(1.f/2048.f)) / 5.656854249492381f + msk;
        }
      }
    }
    __syncthreads();

    // ---- softmax over kcells < 81, rows < 81 ----
    if (tid < 486) {
      const int r = tid/6, j = tid - (tid/6)*6;
      const int kb = j*14;
      float m = -INFINITY;
      for (int c = 0; c < 14; ++c) {
        const int k = kb + c;
        if (k < 81) m = fmaxf(m, SC[r*132 + k]);
      }
      RED[tid] = m;
    }
    __syncthreads();
    if (tid < 81) {
      float m = RED[tid*6];
      #pragma unroll
      for (int j = 1; j < 6; ++j) m = fmaxf(m, RED[tid*6 + j]);
      RMAX[tid] = m;
    }
    __syncthreads();
    if (tid < 486) {
      const int r = tid/6, j = tid - (tid/6)*6;
      const int kb = j*14;
      const float m = RMAX[r];
      float ss = 0.f;
      for (int c = 0; c < 14; ++c) {
        const int k = kb + c;
        if (k < 81) {
          const float e = expf(SC[r*132 + k] - m);
          SC[r*132 + k] = e;
          ss += e;
        }
      }
      RED[tid] = ss;
    }
    __syncthreads();
    if (tid < 81) {
      float ss = 0.f;
      #pragma unroll
      for (int j = 0; j < 6; ++j) ss += RED[tid*6 + j];
      RINV[tid] = 1.0f / ss;
    }
    __syncthreads();

    // ---- probs: read e*rinv (f32, feeds asc), then write fp16 hi/lo ----
    float pv[21];
    #pragma unroll
    for (int i = 0; i < 21; ++i) {
      const int idx = tid + i*512;
      float v = 0.f;
      if (idx < 10368) {
        const int q = idx >> 7, k = idx & 127;
        if (k < 81) v = SC[q*132 + k] * RINV[q];
      }
      pv[i] = v;
      ascR[i] += v;
    }
    __syncthreads();
    #pragma unroll
    for (int i = 0; i < 21; ++i) {
      const int idx = tid + i*512;
      if (idx < 10368) {
        const int q = idx >> 7, k = idx & 127;
        u16 hh, llv;
        splitu(pv[i], hh, llv);
        const uint32_t ad = (uint32_t)q*256u +
            ((((k >> 3) ^ (q & 7))) << 4) + (k & 7)*2;
        *(u16*)(PH + ad) = hh;
        *(u16*)(PL + ad) = llv;
      }
    }
    __syncthreads();

    // ---- ctx^T[hd][cell] = vT · P : 12 tiles (2 ot x 6 nt) ----
    for (int t = wv; t < 12; t += 8) {
      const int ot = t/6, nt = t - (t/6)*6;
      f32x4 aH = (f32x4){0.f,0.f,0.f,0.f};
      f32x4 aC = (f32x4){0.f,0.f,0.f,0.f};
      #pragma unroll
      for (int kc = 0; kc < 3; ++kc) {
        const int ra = ot*16 + lr;
        const uint32_t oa = (uint32_t)ra*256u +
            ((((kc*4 + lg) ^ (ra & 7))) << 4);
        const f16x8 Vh = *(const f16x8*)(VTH + oa);
        const f16x8 Vl = *(const f16x8*)(VTL + oa);
        const int rb = nt*16 + lr;
        const uint32_t ob = (uint32_t)rb*256u +
            ((((kc*4 + lg) ^ (rb & 7))) << 4);
        const f16x8 Pf = *(const f16x8*)(PH + ob);
        const f16x8 Pl2 = *(const f16x8*)(PL + ob);
        aH = __builtin_amdgcn_mfma_f32_16x16x32_f16(Vh, Pf,  aH, 0,0,0);
        aC = __builtin_amdgcn_mfma_f32_16x16x32_f16(Vh, Pl2, aC, 0,0,0);
        aC = __builtin_amdgcn_mfma_f32_16x16x32_f16(Vl, Pf,  aC, 0,0,0);
      }
      const int cell = nt*16 + lr;
      if (cell < 81) {
        float* cb = ctxg + ((size_t)b*128 + h*32 + ot*16 + lg*4)*81 + cell;
        #pragma unroll
        for (int r = 0; r < 4; ++r)
          cb[(size_t)r*81] = aH[r] + aC[r]*(1.f/2048.f);
      }
    }
    __syncthreads();
  } // heads

  // asc = mean over heads
  #pragma unroll
  for (int i = 0; i < 21; ++i) {
    const int idx = tid + i*512;
    if (idx < 10368) {
      const int q = idx >> 7, k = idx & 127;
      if (k < 81) asc[(size_t)b*6561 + q*81 + k] = 0.25f * ascR[i];
    }
  }
}

// ---------------- post: out-proj, LN, l1, l2, heads + sampling -------------
__global__ __launch_bounds__(256) void k_post(
    const float* __restrict__ ctxg,
    const float* __restrict__ owT,  const float* __restrict__ out_b,
    const float* __restrict__ ln_g, const float* __restrict__ ln_b,
    const float* __restrict__ l1T,  const float* __restrict__ l1_b,
    const float* __restrict__ l2T,  const float* __restrict__ l2_b,
    const float* __restrict__ pos_w, const float* __restrict__ pos_b,
    const float* __restrict__ num_w, const float* __restrict__ num_b,
    const int* __restrict__ digits,  float* __restrict__ dout)
{
  __shared__ float yT[128*84];
  __shared__ float red[243];
  __shared__ float mu[81], rstd[81];
  __shared__ float vals[81];
  __shared__ int   posIdx;
  const int b   = blockIdx.x;
  const int tid = threadIdx.x;
  const int ocg = tid >> 3;   // 0..31
  const int ng  = tid & 7;    // 0..7 (ng==7 idle in GEMMs)

  // stage ctx (global [b][128][81]) -> yT[k][n]; zero pad cols 81..83
  {
    const float* cb = ctxg + (size_t)b*128*81;
    for (int i = tid; i < 128*81; i += 256) {
      int k = i / 81, n = i - k*81;
      yT[k*84 + n] = cb[i];
    }
    for (int i = tid; i < 128*3; i += 256) {
      int k = i / 3, c = i - k*3;
      yT[k*84 + 81 + c] = 0.f;
    }
  }
  __syncthreads();

  // ---- out projection (reads yT as ctx, writes yT as y) ----
  {
    float4 acc[4][3];
    #pragma unroll
    for (int c = 0; c < 4; ++c)
      { acc[c][0]=zero4(); acc[c][1]=zero4(); acc[c][2]=zero4(); }
    if (ng < 7) {
      #pragma unroll 2
      for (int k = 0; k < 128; ++k) {
        const float4 wv = *(const float4*)(owT + k*128 + ocg*4);
        const float* yr = yT + k*84 + ng*12;
        float4 x0 = *(const float4*)(yr);
        float4 x1 = *(const float4*)(yr + 4);
        float4 x2 = *(const float4*)(yr + 8);
        fma4b(acc[0][0], wv.x, x0); fma4b(acc[0][1], wv.x, x1); fma4b(acc[0][2], wv.x, x2);
        fma4b(acc[1][0], wv.y, x0); fma4b(acc[1][1], wv.y, x1); fma4b(acc[1][2], wv.y, x2);
        fma4b(acc[2][0], wv.z, x0); fma4b(acc[2][1], wv.z, x1); fma4b(acc[2][2], wv.z, x2);
        fma4b(acc[3][0], wv.w, x0); fma4b(acc[3][1], wv.w, x1); fma4b(acc[3][2], wv.w, x2);
      }
    }
    __syncthreads();
    if (ng < 7) {
      #pragma unroll
      for (int c = 0; c < 4; ++c) {
        const float bv = out_b[ocg*4 + c];
        #pragma unroll
        for (int t = 0; t < 3; ++t) {
          float4 o = acc[c][t];
          o.x += bv; o.y += bv; o.z += bv; o.w += bv;
          *(float4*)(yT + (ocg*4 + c)*84 + ng*12 + t*4) = o;
        }
      }
    }
  }
  __syncthreads();

  // ---- LayerNorm over k (columns n) ----
  if (tid < 243) {
    const int n = tid/3, j = tid - (tid/3)*3;
    float ssum = 0.f;
    for (int c = 0; c < 43; ++c) {
      int k = j*43 + c;
      if (k < 128) ssum += yT[k*84 + n];
    }
    red[tid] = ssum;
  }
  __syncthreads();
  if (tid < 81)
    mu[tid] = (red[tid*3] + red[tid*3+1] + red[tid*3+2]) * (1.0f/128.0f);
  __syncthreads();
  if (tid < 243) {
    const int n = tid/3, j = tid - (tid/3)*3;
    const float m = mu[n];
    float ssum = 0.f;
    for (int c = 0; c < 43; ++c) {
      int k = j*43 + c;
      if (k < 128) { float d = yT[k*84 + n] - m; ssum += d*d; }
    }
    red[tid] = ssum;
  }
  __syncthreads();
  if (tid < 81) {
    float v = (red[tid*3] + red[tid*3+1] + red[tid*3+2]) * (1.0f/128.0f);
    rstd[tid] = 1.0f / sqrtf(v + 1e-5f);
  }
  __syncthreads();
  for (int i = tid; i < 128*81; i += 256) {
    const int k = i / 81, n = i - k*81;
    yT[k*84 + n] = (yT[k*84 + n] - mu[n]) * rstd[n] * ln_g[k] + ln_b[k];
  }
  __syncthreads();

  // ---- l1 (silu) ----
  {
    float4 acc[4][3];
    #pragma unroll
    for (int c = 0; c < 4; ++c)
      { acc[c][0]=zero4(); acc[c][1]=zero4(); acc[c][2]=zero4(); }
    if (ng < 7) {
      #pragma unroll 2
      for (int k = 0; k < 128; ++k) {
        const float4 wv = *(const float4*)(l1T + k*128 + ocg*4);
        const float* yr = yT + k*84 + ng*12;
        float4 x0 = *(const float4*)(yr);
        float4 x1 = *(const float4*)(yr + 4);
        float4 x2 = *(const float4*)(yr + 8);
        fma4b(acc[0][0], wv.x, x0); fma4b(acc[0][1], wv.x, x1); fma4b(acc[0][2], wv.x, x2);
        fma4b(acc[1][0], wv.y, x0); fma4b(acc[1][1], wv.y, x1); fma4b(acc[1][2], wv.y, x2);
        fma4b(acc[2][0], wv.z, x0); fma4b(acc[2][1], wv.z, x1); fma4b(acc[2][2], wv.z, x2);
        fma4b(acc[3][0], wv.w, x0); fma4b(acc[3][1], wv.w, x1); fma4b(acc[3][2], wv.w, x2);
      }
    }
    __syncthreads();
    if (ng < 7) {
      #pragma unroll
      for (int c = 0; c < 4; ++c) {
        const float bv = l1_b[ocg*4 + c];
        #pragma unroll
        for (int t = 0; t < 3; ++t) {
          float4 o = acc[c][t];
          o.x = silu_f(o.x + bv); o.y = silu_f(o.y + bv);
          o.z = silu_f(o.z + bv); o.w = silu_f(o.w + bv);
          *(float4*)(yT + (ocg*4 + c)*84 + ng*12 + t*4) = o;
        }
      }
    }
  }
  __syncthreads();

  // ---- l2 (silu) ----
  {
    float4 acc[4][3];
    #pragma unroll
    for (int c = 0; c < 4; ++c)
      { acc[c][0]=zero4(); acc[c][1]=zero4(); acc[c][2]=zero4(); }
    if (ng < 7) {
      #pragma unroll 2
      for (int k = 0; k < 128; ++k) {
        const float4 wv = *(const float4*)(l2T + k*128 + ocg*4);
        const float* yr = yT + k*84 + ng*12;
        float4 x0 = *(const float4*)(yr);
        float4 x1 = *(const float4*)(yr + 4);
        float4 x2 = *(const float4*)(yr + 8);
        fma4b(acc[0][0], wv.x, x0); fma4b(acc[0][1], wv.x, x1); fma4b(acc[0][2], wv.x, x2);
        fma4b(acc[1][0], wv.y, x0); fma4b(acc[1][1], wv.y, x1); fma4b(acc[1][2], wv.y, x2);
        fma4b(acc[2][0], wv.z, x0); fma4b(acc[2][1], wv.z, x1); fma4b(acc[2][2], wv.z, x2);
        fma4b(acc[3][0], wv.w, x0); fma4b(acc[3][1], wv.w, x1); fma4b(acc[3][2], wv.w, x2);
      }
    }
    __syncthreads();
    if (ng < 7) {
      #pragma unroll
      for (int c = 0; c < 4; ++c) {
        const float bv = l2_b[ocg*4 + c];
        #pragma unroll
        for (int t = 0; t < 3; ++t) {
          float4 o = acc[c][t];
          o.x = silu_f(o.x + bv); o.y = silu_f(o.y + bv);
          o.z = silu_f(o.z + bv); o.w = silu_f(o.w + bv);
          *(float4*)(yT + (ocg*4 + c)*84 + ng*12 + t*4) = o;
        }
      }
    }
  }
  __syncthreads();

  // ---- position head + gumbel sampling ----
  uint32_t k1a, k1b, k2a, k2b;
  jax_split42(k1a, k1b, k2a, k2b);

  if (tid < 243) {
    const int n = tid/3, j = tid - (tid/3)*3;
    float ssum = 0.f;
    for (int c = 0; c < 43; ++c) {
      int k = j*43 + c;
      if (k < 128) ssum += yT[k*84 + n] * pos_w[k];
    }
    red[tid] = ssum;
  }
  __syncthreads();
  if (tid < 81) {
    float acc = red[tid*3] + red[tid*3+1] + red[tid*3+2] + pos_b[0];
    if (digits[b*81 + tid] != 0) acc = -1e9f;
    uint32_t bits = jax_randbits(k1a, k1b, (uint32_t)(b*81 + tid));
    vals[tid] = acc + jax_gumbel_bits(bits);
  }
  __syncthreads();
  if (tid == 0) {
    float best = vals[0]; int bi = 0;
    for (int n = 1; n < 81; ++n)
      if (vals[n] > best) { best = vals[n]; bi = n; }
    posIdx = bi;
    dout[b] = (float)bi;
  }
  __syncthreads();
  const int pos = posIdx;

  // ---- number head at sampled position ----
  if (tid < 80) {
    const int d = tid >> 3, j = tid & 7;
    float ssum = 0.f;
    #pragma unroll
    for (int c = 0; c < 16; ++c) {
      int k = j*16 + c;
      ssum += yT[k*84 + pos] * num_w[d*128 + k];
    }
    red[tid] = ssum;
  }
  __syncthreads();
  if (tid < 10) {
    float acc = num_b[tid];
    #pragma unroll
    for (int j = 0; j < 8; ++j) acc += red[tid*8 + j];
    if (tid == 0) acc = -INFINITY;
    uint32_t bits = jax_randbits(k2a, k2b, (uint32_t)(b*10 + tid));
    vals[tid] = acc + jax_gumbel_bits(bits);
  }
  __syncthreads();
  if (tid == 0) {
    float best = vals[0]; int bi = 0;
    for (int d = 1; d < 10; ++d)
      if (vals[d] > best) { best = vals[d]; bi = d; }
    dout[NB + b] = (float)bi;
  }
}

// ---------------------------------------------------------------------------
extern "C" void kernel_launch(void* const* d_in, const int* in_sizes, int n_in,
                              void* d_out, int out_size, void* d_ws, size_t ws_size,
                              hipStream_t stream) {
  const float* s     = (const float*)d_in[0];
  const float* c1_w  = (const float*)d_in[1];
  const float* c1_b  = (const float*)d_in[2];
  const float* c2_w  = (const float*)d_in[3];
  const float* c2_b  = (const float*)d_in[4];
  const float* c3_w  = (const float*)d_in[5];
  const float* c3_b  = (const float*)d_in[6];
  const float* emb   = (const float*)d_in[7];
  const float* in_w  = (const float*)d_in[8];
  const float* in_b  = (const float*)d_in[9];
  const float* out_w = (const float*)d_in[10];
  const float* out_b = (const float*)d_in[11];
  const float* ln_g  = (const float*)d_in[12];
  const float* ln_b  = (const float*)d_in[13];
  const float* l1_w  = (const float*)d_in[14];
  const float* l1_b  = (const float*)d_in[15];
  const float* l2_w  = (const float*)d_in[16];
  const float* l2_b  = (const float*)d_in[17];
  const float* pos_w = (const float*)d_in[18];
  const float* pos_b = (const float*)d_in[19];
  const float* num_w = (const float*)d_in[20];
  const float* num_b = (const float*)d_in[21];

  // ws layout (floats):
  // T2e 0 (12672) | WAh 12672 (73728 f = 147456 u16) | WAl 86400 (73728 f) |
  // owT 160128 (16384) | l1T 176512 (16384) | l2T 192896 (16384) |
  // digits 209280 (331776 int) | x 541056 (42467328) | ctxg 43008384
  float* ws     = (float*)d_ws;
  float* T2e    = ws;
  u16*   WAh    = (u16*)(ws + 12672);
  u16*   WAl    = (u16*)(ws + 86400);
  float* owT    = ws + 160128;
  float* l1T    = ws + 176512;
  float* l2T    = ws + 192896;
  int*   digits = (int*)(ws + 209280);
  float* x      = ws + 541056;
  float* ctxg   = ws + 43008384;

  float* dout = (float*)d_out;
  float* asc  = dout + 2*NB;

  hipFuncSetAttribute((const void*)k_attn,
                      hipFuncAttributeMaxDynamicSharedMemorySize,
                      ATTN_LDS_BYTES);

  k_prep<<<dim3(818), dim3(256), 0, stream>>>(
      c1_w, c1_b, c2_w, c3_w, out_w, l1_w, l2_w,
      T2e, WAh, WAl, owT, l1T, l2T);
  k_stem<<<dim3(NB), dim3(256), 0, stream>>>(
      s, T2e, c2_b, WAh, WAl, c3_b, emb, x, digits);
  k_attn<<<dim3(NB), dim3(512), ATTN_LDS_BYTES, stream>>>(
      x, in_w, in_b, ctxg, asc);
  k_post<<<dim3(NB), dim3(256), 0, stream>>>(
      ctxg, owT, out_b, ln_g, ln_b, l1T, l1_b, l2T, l2_b,
      pos_w, pos_b, num_w, num_b, digits, dout);
}